// Round 1
// baseline (162.053 us; speedup 1.0000x reference)
//
#include <hip/hip_runtime.h>
#include <hip/hip_bf16.h>

typedef unsigned short u16;
typedef __bf16 bf16x8 __attribute__((ext_vector_type(8)));
typedef float f32x4 __attribute__((ext_vector_type(4)));

#define AS1 __attribute__((address_space(1)))
#define AS3 __attribute__((address_space(3)))

__device__ inline void gload_lds16(const void* g, void* l) {
    __builtin_amdgcn_global_load_lds((const AS1 void*)g, (AS3 void*)l, 16, 0, 0);
}

__device__ inline u16 f2bf(float f) {
    __hip_bfloat16 h = __float2bfloat16(f);
    return __builtin_bit_cast(u16, h);
}

// ---------------------------------------------------------------------------
// fp32 -> bf16 convert, 4 elements/thread
// ---------------------------------------------------------------------------
__global__ __launch_bounds__(256)
void cvt_f32_bf16(const float4* __restrict__ in, u16* __restrict__ out, int n4) {
    int i = blockIdx.x * 256 + threadIdx.x;
    if (i >= n4) return;
    float4 v = in[i];
    uint2 pk;
    pk.x = (unsigned)f2bf(v.x) | ((unsigned)f2bf(v.y) << 16);
    pk.y = (unsigned)f2bf(v.z) | ((unsigned)f2bf(v.w) << 16);
    *(uint2*)(out + (long long)i * 4) = pk;
}

// ---------------------------------------------------------------------------
// bf16 transpose within each batch: Vt[b][d][k] = V[b][k][d]
// ---------------------------------------------------------------------------
__global__ __launch_bounds__(256)
void transpose_v(const u16* __restrict__ V, u16* __restrict__ Vt) {
    __shared__ u16 tile[32][33];
    const int b  = blockIdx.z;
    const int d0 = blockIdx.x * 32;
    const int k0 = blockIdx.y * 32;
    const int tx = threadIdx.x & 31;
    const int ty = threadIdx.x >> 5;  // 0..7
    #pragma unroll
    for (int r = ty; r < 32; r += 8)
        tile[r][tx] = V[((long long)b * 1024 + k0 + r) * 1024 + d0 + tx];
    __syncthreads();
    #pragma unroll
    for (int r = ty; r < 32; r += 8)
        Vt[((long long)b * 1024 + d0 + r) * 1024 + k0 + tx] = tile[tx][r];
}

// ---------------------------------------------------------------------------
// m97-structure bf16 GEMM, B^T layout: C[m][n] = sum_k A[m][k] * Bt[n][k]
// MODE 0: proj  (bias by blockIdx.z, bf16 out)
// MODE 1: scores (f32 out, * scale, skip blocks strictly above diagonal)
// MODE 2: pv    (f32 out, K-loop limited to row0+BM  — causal)
// ---------------------------------------------------------------------------
template<int MODE>
__global__ __launch_bounds__(256)
void gemm_bt(const u16* __restrict__ A, long long strideA,
             const u16* __restrict__ Bt, long long strideB,
             void* __restrict__ Cv, long long strideC,
             const float* __restrict__ bias0, const float* __restrict__ bias1,
             const float* __restrict__ bias2,
             int M, int N, int K, float scale)
{
    constexpr int BM = 128, BN = 128, BK = 32;
    __shared__ __align__(16) u16 shA[BM * BK];
    __shared__ __align__(16) u16 shB[BN * BK];
    const int bz   = blockIdx.z;
    const int row0 = blockIdx.y * BM;
    const int col0 = blockIdx.x * BN;
    if (MODE == 1 && col0 > row0) return;  // fully-masked causal block
    const u16* Ab = A  + (long long)bz * strideA;
    const u16* Bb = Bt + (long long)bz * strideB;
    int kEnd = K;
    if (MODE == 2) kEnd = (row0 + BM < K) ? (row0 + BM) : K;

    const int t  = (int)threadIdx.x;
    const int l  = t & 63;
    const int w  = t >> 6;
    const int wr = w >> 1, wc = w & 1;
    const int fr = l & 15, fq = l >> 4;

    f32x4 acc[4][4];
    const f32x4 zero = {0.f, 0.f, 0.f, 0.f};
    #pragma unroll
    for (int m = 0; m < 4; ++m)
        #pragma unroll
        for (int n = 0; n < 4; ++n)
            acc[m][n] = zero;

    for (int kk = 0; kk < kEnd; kk += BK) {
        if (kk) __syncthreads();
        #pragma unroll
        for (int r = 0; r < 2; ++r) {
            const int s    = t + r * 256;       // 16B slot index
            const int rrow = s >> 2;            // tile row (of 128)
            const int rcol = (s & 3) << 3;      // bf16 column offset (0,8,16,24)
            gload_lds16(Ab + (long long)(row0 + rrow) * K + kk + rcol, (void*)(shA + s * 8));
            gload_lds16(Bb + (long long)(col0 + rrow) * K + kk + rcol, (void*)(shB + s * 8));
        }
        __syncthreads();
        bf16x8 aF[4], bF[4];
        #pragma unroll
        for (int m = 0; m < 4; ++m)
            aF[m] = *(const bf16x8*)(shA + (wr * 64 + m * 16 + fr) * BK + fq * 8);
        #pragma unroll
        for (int n = 0; n < 4; ++n)
            bF[n] = *(const bf16x8*)(shB + (wc * 64 + n * 16 + fr) * BK + fq * 8);
        #pragma unroll
        for (int m = 0; m < 4; ++m)
            #pragma unroll
            for (int n = 0; n < 4; ++n)
                acc[m][n] = __builtin_amdgcn_mfma_f32_16x16x32_bf16(aF[m], bF[n], acc[m][n], 0, 0, 0);
    }

    if (MODE == 0) {
        const float* bp = (bz == 0) ? bias0 : ((bz == 1) ? bias1 : bias2);
        u16* C = (u16*)Cv + (long long)bz * strideC;
        #pragma unroll
        for (int n = 0; n < 4; ++n) {
            const int cn = col0 + wc * 64 + n * 16 + fr;
            const float bv = bp[cn];
            #pragma unroll
            for (int m = 0; m < 4; ++m) {
                const int cm = row0 + wr * 64 + m * 16 + fq * 4;
                #pragma unroll
                for (int j = 0; j < 4; ++j)
                    C[(long long)(cm + j) * N + cn] = f2bf(acc[m][n][j] + bv);
            }
        }
    } else {
        float* C = (float*)Cv + (long long)bz * strideC;
        #pragma unroll
        for (int n = 0; n < 4; ++n) {
            const int cn = col0 + wc * 64 + n * 16 + fr;
            #pragma unroll
            for (int m = 0; m < 4; ++m) {
                const int cm = row0 + wr * 64 + m * 16 + fq * 4;
                #pragma unroll
                for (int j = 0; j < 4; ++j)
                    C[(long long)(cm + j) * N + cn] = acc[m][n][j] * scale;
            }
        }
    }
}

// ---------------------------------------------------------------------------
// causal row softmax: P[row][j] = softmax(S[row][0..q]) as bf16, 0 for j>q
// one block per row (row = b*1024 + q), 256 threads * 4 elems
// ---------------------------------------------------------------------------
__global__ __launch_bounds__(256)
void softmax_causal(const float* __restrict__ S, u16* __restrict__ P) {
    __shared__ float redM[4], redS[4];
    const int row = blockIdx.x;
    const int q   = row & 1023;
    const int t   = (int)threadIdx.x;
    const int l   = t & 63, w = t >> 6;
    const float4* srow = (const float4*)(S + (long long)row * 1024);
    float4 v = srow[t];
    const int j0 = t * 4;
    float x0 = (j0 + 0 <= q) ? v.x : -1e30f;
    float x1 = (j0 + 1 <= q) ? v.y : -1e30f;
    float x2 = (j0 + 2 <= q) ? v.z : -1e30f;
    float x3 = (j0 + 3 <= q) ? v.w : -1e30f;
    float m = fmaxf(fmaxf(x0, x1), fmaxf(x2, x3));
    #pragma unroll
    for (int o = 32; o > 0; o >>= 1) m = fmaxf(m, __shfl_xor(m, o, 64));
    if (l == 0) redM[w] = m;
    __syncthreads();
    m = fmaxf(fmaxf(redM[0], redM[1]), fmaxf(redM[2], redM[3]));
    float e0 = __expf(x0 - m);
    float e1 = __expf(x1 - m);
    float e2 = __expf(x2 - m);
    float e3 = __expf(x3 - m);
    float s = e0 + e1 + e2 + e3;
    #pragma unroll
    for (int o = 32; o > 0; o >>= 1) s += __shfl_xor(s, o, 64);
    if (l == 0) redS[w] = s;
    __syncthreads();
    s = redS[0] + redS[1] + redS[2] + redS[3];
    const float inv = 1.0f / s;
    uint2 pk;
    pk.x = (unsigned)f2bf(e0 * inv) | ((unsigned)f2bf(e1 * inv) << 16);
    pk.y = (unsigned)f2bf(e2 * inv) | ((unsigned)f2bf(e3 * inv) << 16);
    *(uint2*)(P + (long long)row * 1024 + j0) = pk;
}

// ---------------------------------------------------------------------------
extern "C" void kernel_launch(void* const* d_in, const int* in_sizes, int n_in,
                              void* d_out, int out_size, void* d_ws, size_t ws_size,
                              hipStream_t stream) {
    const float* x  = (const float*)d_in[0];
    const float* Wq = (const float*)d_in[1];
    const float* bq = (const float*)d_in[2];
    const float* Wk = (const float*)d_in[3];
    const float* bk = (const float*)d_in[4];
    const float* Wv = (const float*)d_in[5];
    const float* bv = (const float*)d_in[6];
    float* out = (float*)d_out;
    char* ws = (char*)d_ws;

    // workspace layout (134 MB total)
    u16*   xb  = (u16*)(ws + 0);                      // 16 MB  [8192][1024] bf16
    u16*   Wb  = (u16*)(ws + ((size_t)16 << 20));     //  6 MB  [3][1024][1024] bf16
    u16*   QKV = (u16*)(ws + ((size_t)22 << 20));     // 48 MB  [3][8192][1024] bf16
    u16*   Vt  = (u16*)(ws + ((size_t)70 << 20));     // 16 MB  [8][1024][1024] bf16 (d,k)
    float* SC  = (float*)(ws + ((size_t)86 << 20));   // 32 MB  [8][1024][1024] f32
    u16*   P   = (u16*)(ws + ((size_t)118 << 20));    // 16 MB  [8][1024][1024] bf16

    // 1) convert to bf16
    cvt_f32_bf16<<<8192, 256, 0, stream>>>((const float4*)x, xb, 8388608 / 4);
    cvt_f32_bf16<<<1024, 256, 0, stream>>>((const float4*)Wq, Wb, 1048576 / 4);
    cvt_f32_bf16<<<1024, 256, 0, stream>>>((const float4*)Wk, Wb + 1048576, 1048576 / 4);
    cvt_f32_bf16<<<1024, 256, 0, stream>>>((const float4*)Wv, Wb + 2097152, 1048576 / 4);

    // 2) Q,K,V projections (grid.z selects weight/bias/output)
    gemm_bt<0><<<dim3(8, 64, 3), 256, 0, stream>>>(xb, 0LL, Wb, 1048576LL, QKV, 8388608LL,
                                                   bq, bk, bv, 8192, 1024, 1024, 1.0f);

    // 3) V transpose for PV gemm
    transpose_v<<<dim3(32, 32, 8), 256, 0, stream>>>(QKV + 2 * 8388608LL, Vt);

    // 4) scores = Q K^T / 32 (causal block skip)
    gemm_bt<1><<<dim3(8, 8, 8), 256, 0, stream>>>(QKV, 1048576LL, QKV + 8388608LL, 1048576LL,
                                                  SC, 1048576LL,
                                                  nullptr, nullptr, nullptr,
                                                  1024, 1024, 1024, 0.03125f);

    // 5) causal softmax -> P (bf16)
    softmax_causal<<<8192, 256, 0, stream>>>(SC, P);

    // 6) O = P V   (K-loop causally limited)
    gemm_bt<2><<<dim3(8, 8, 8), 256, 0, stream>>>(P, 1048576LL, Vt, 1048576LL, out, 1048576LL,
                                                  nullptr, nullptr, nullptr,
                                                  1024, 1024, 1024, 1.0f);
}